// Round 17
// baseline (97.125 us; speedup 1.0000x reference)
//
#include <hip/hip_runtime.h>
#include <hip/hip_bf16.h>
#include <math.h>

#define B_ 64
#define T_ 512
#define D_ 768
#define H_ 96
#define M_ (B_*T_)   // 32768 rows

typedef __attribute__((ext_vector_type(8))) short short8;
typedef __attribute__((ext_vector_type(4))) float f32x4;
typedef __attribute__((ext_vector_type(4))) unsigned uint4v;

__device__ __forceinline__ short f2bf(float f) {
  unsigned u = __float_as_uint(f);
  unsigned r = (u + 0x7FFFu + ((u >> 16) & 1u)) >> 16;   // RTNE
  return (short)r;
}

__device__ __forceinline__ unsigned cvtpk(float lo, float hi) {  // 2xf32 -> 2xbf16
  unsigned r;
  asm("v_cvt_pk_bf16_f32 %0, %1, %2" : "=v"(r) : "v"(lo), "v"(hi));
  return r;
}

__device__ __forceinline__ void gl16(const void* g, void* l) {
  __builtin_amdgcn_global_load_lds(
      (const __attribute__((address_space(1))) unsigned*)g,
      (__attribute__((address_space(3))) unsigned*)l, 16, 0, 0);
}

// ---------------------------------------------------------------------------
// Kernel 0: W -> bf16, transposed to [n][k] (n = mi*96+cc, 288 x 768).
// ---------------------------------------------------------------------------
__global__ __launch_bounds__(256) void wt_kernel(
    const float* __restrict__ Wq, const float* __restrict__ Wk,
    const float* __restrict__ Wv, short* __restrict__ wt)
{
  int id = blockIdx.x * 256 + threadIdx.x;     // 3*96*768 = 221184
  if (id >= 3*H_*D_) return;
  int n = id % 288;
  int k = id / 288;
  int mi = n / 96, cc = n % 96;
  const float* Wm = (mi == 0) ? Wq : ((mi == 1) ? Wk : Wv);
  wt[(size_t)n * D_ + k] = f2bf(Wm[(size_t)k * H_ + cc]);
}

// ---------------------------------------------------------------------------
// Kernel 1: QKV projection — A-resident structure.
// Rounds 5-16 invariance: qkv pinned at 57-64 us across BK, occupancy,
// staging scheme, pipeline depth.  The one constant: x fetched as 128B
// k-slices at 3072B row stride -> strided-DRAM efficiency ~25% (100MB/58us
// = 1.7 TB/s effective; poison fills prove 7 TB/s contiguous).  Fix: stage
// the block's 64 x-rows ONCE, contiguously (196KB float4 stream), convert
// to bf16, keep resident in 96KB LDS (chunk-XOR c^(row&7), 2-way-free).
// K-loop stages only the L2-resident W tile (R12-verbatim stageB); barrier
// drain now covers ~300cyc L2, not strided HBM.  Wave tile 32x144 (2x9).
// ---------------------------------------------------------------------------
#define BKP 32
#define BBYTES 18432            // 288 rows x 32 bf16

__global__ __launch_bounds__(256) void qkv_mfma_kernel(
    const float* __restrict__ x, const short* __restrict__ wt,
    short* __restrict__ qb, short* __restrict__ kb, short* __restrict__ vb)
{
  __shared__ short Ab[64 * 768];      // 98,304 B resident bf16 A-panel
  __shared__ short Bs[2][288][32];    // 36,864 B   (total 135,168)

  const int t    = threadIdx.x;
  const int row0 = blockIdx.x * 64;
  const int lane = t & 63;
  const int w    = t >> 6;
  const int wr   = w >> 1;            // row half: rows wr*32..+32
  const int wc   = w & 1;             // col half: cols wc*144..+144
  const int l15  = lane & 15;
  const int l4   = lane >> 4;

  // ---- one-time A stage: 64 rows x 768 fp32, CONTIGUOUS reads ----
  // 6144 16B-bf16 chunks (8 fp32 source each); 24 per thread; consecutive
  // threads -> consecutive 32B source (perfect coalescing).
  #pragma unroll
  for (int i = 0; i < 24; ++i) {
    int id  = t + i * 256;            // 0..6143
    int row = id / 96;
    int c   = id % 96;                // 16B-chunk within row
    const float* src = x + (size_t)(row0 + row) * D_ + c * 8;
    float4 f0 = *reinterpret_cast<const float4*>(src);
    float4 f1 = *reinterpret_cast<const float4*>(src + 4);
    uint4v uv;
    uv[0] = cvtpk(f0.x, f0.y); uv[1] = cvtpk(f0.z, f0.w);
    uv[2] = cvtpk(f1.x, f1.y); uv[3] = cvtpk(f1.z, f1.w);
    *reinterpret_cast<short8*>(&Ab[row * 768 + ((c ^ (row & 7)) * 8)]) =
        *reinterpret_cast<short8*>(&uv);
  }

  // ---- B staging: R12-verbatim global_load_lds (wt is L2-resident) ----
  auto stageB = [&](int buf, int k0) {
    #pragma unroll
    for (int i = 0; i < 5; ++i) {
      int inst = w + 4 * i;                     // 0..19, guard to 18
      if (inst < 18) {
        int row = inst * 16 + (lane >> 2);      // 0..287
        int c16 = (lane & 3) ^ ((lane >> 2) & 3);
        const char* g = (const char*)(wt + (size_t)row * D_ + k0) + c16 * 16;
        char* l = (char*)&Bs[buf][0][0] + inst * 1024 + lane * 16;
        gl16(g, l);
      }
    }
  };

  f32x4 acc[2][9];
  #pragma unroll
  for (int ri = 0; ri < 2; ++ri)
    #pragma unroll
    for (int ci = 0; ci < 9; ++ci) acc[ri][ci] = (f32x4){0.f, 0.f, 0.f, 0.f};

  stageB(0, 0);
  __syncthreads();                    // covers A-panel + B buffer 0

  const char* Bbase = (const char*)&Bs[0][0][0];

  for (int ks = 0; ks < 24; ++ks) {
    int buf = ks & 1;
    if (ks + 1 < 24) stageB(buf ^ 1, (ks + 1) * BKP);

    // A-frags from resident panel: chunk = ks*4 + l4, un-XOR per row
    short8 af[2];
    #pragma unroll
    for (int ri = 0; ri < 2; ++ri) {
      int row = wr * 32 + ri * 16 + l15;
      int chunk = ks * 4 + l4;
      af[ri] = *reinterpret_cast<const short8*>(
          &Ab[row * 768 + ((chunk ^ (row & 7)) * 8)]);
    }
    #pragma unroll
    for (int ci = 0; ci < 9; ++ci) {
      int brow = wc * 144 + ci * 16 + l15;
      short8 bf = *reinterpret_cast<const short8*>(
          Bbase + (size_t)buf * BBYTES + brow * 64 + ((l4 ^ (brow & 3)) * 16));
      acc[0][ci] = __builtin_amdgcn_mfma_f32_16x16x32_bf16(af[0], bf, acc[0][ci], 0, 0, 0);
      acc[1][ci] = __builtin_amdgcn_mfma_f32_16x16x32_bf16(af[1], bf, acc[1][ci], 0, 0, 0);
    }
    __syncthreads();                  // drains only B (L2-fast)
  }

  // epilogue: frag (ri,ci): rows row0+wr*32+ri*16+l4*4+reg,
  //                         global col wc*144+ci*16+l15
  #pragma unroll
  for (int ci = 0; ci < 9; ++ci) {
    int ncol = wc * 144 + ci * 16;
    int mi   = ncol / 96;             // wave-uniform
    int cc   = ncol % 96 + l15;
    short* Om = (mi == 0) ? qb : ((mi == 1) ? kb : vb);
    #pragma unroll
    for (int ri = 0; ri < 2; ++ri) {
      int rbase = row0 + wr * 32 + ri * 16 + l4 * 4;
      #pragma unroll
      for (int reg = 0; reg < 4; ++reg)
        Om[(size_t)(rbase + reg) * H_ + cc] = f2bf(acc[ri][ci][reg]);
    }
  }
}

// ---------------------------------------------------------------------------
// Kernel 2: causal flash attention via MFMA bf16 (round-13 version, verified).
// ---------------------------------------------------------------------------
#define QB 32
#define KVB 32
#define KSTR 104
#define VSTR 40
#define PSTR 40

__global__ __launch_bounds__(128) void attn_mfma_kernel(
    const short* __restrict__ qb, const short* __restrict__ kb,
    const short* __restrict__ vb, float* __restrict__ out)
{
  __shared__ short ks[KVB][KSTR];     // 6656 B
  __shared__ short vs[H_][VSTR];      // 7680 B
  __shared__ short ps[2][16][PSTR];   // 2560 B

  const int t    = threadIdx.x;
  const int lane = t & 63;
  const int w    = t >> 6;            // 0..1
  const int l15  = lane & 15;
  const int l4   = lane >> 4;
  const int qi   = 15 - blockIdx.x;   // heavy blocks first
  const int b    = blockIdx.y;
  const int q0   = qi * QB;

  short8 qf[3];
  {
    const short* qbase = qb + ((size_t)(b * T_) + q0 + w * 16 + l15) * H_;
    #pragma unroll
    for (int f = 0; f < 3; ++f)
      qf[f] = *reinterpret_cast<const short8*>(qbase + f * 32 + l4 * 8);
  }

  f32x4 acc[6];
  #pragma unroll
  for (int c = 0; c < 6; ++c) acc[c] = (f32x4){0.f, 0.f, 0.f, 0.f};
  float m_r[4] = {-INFINITY, -INFINITY, -INFINITY, -INFINITY};
  float l_r[4] = {0.f, 0.f, 0.f, 0.f};
  const float scale = 0.10206207261596576f;   // 1/sqrt(96)

  const int jmax = q0 + QB;
  for (int j0 = 0; j0 < jmax; j0 += KVB) {
    __syncthreads();
    {  // stage K tile: 32 rows x 96 bf16
      int row = t >> 2, seg = t & 3;
      const short* src = kb + ((size_t)(b * T_) + j0 + row) * H_ + seg * 24;
      short* dst = &ks[row][seg * 24];
      *reinterpret_cast<short8*>(dst)      = *reinterpret_cast<const short8*>(src);
      *reinterpret_cast<short8*>(dst + 8)  = *reinterpret_cast<const short8*>(src + 8);
      *reinterpret_cast<short8*>(dst + 16) = *reinterpret_cast<const short8*>(src + 16);
    }
    {  // stage V tile: transpose 32 tok x 96 h -> vs[h][tokS]
      #pragma unroll
      for (int i = 0; i < 3; ++i) {
        int c = t + i * 128;            // 0..383
        int tok = c / 12;               // 0..31
        int m   = c % 12;               // h-group (h0 = 8m)
        int h0  = m * 8;
        short8 v = *reinterpret_cast<const short8*>(
            vb + (size_t)(b * T_ + j0 + tok) * H_ + h0);
        int tokS = tok ^ ((m & 3) << 3);     // swizzled tok slot
        #pragma unroll
        for (int j = 0; j < 8; ++j) vs[h0 + j][tokS] = v[j];
      }
    }
    __syncthreads();

    f32x4 sfr[2];
    sfr[0] = (f32x4){0.f,0.f,0.f,0.f};
    sfr[1] = (f32x4){0.f,0.f,0.f,0.f};
    #pragma unroll
    for (int ct = 0; ct < 2; ++ct)
      #pragma unroll
      for (int f = 0; f < 3; ++f) {
        short8 kf = *reinterpret_cast<const short8*>(&ks[ct * 16 + l15][f * 32 + l4 * 8]);
        sfr[ct] = __builtin_amdgcn_mfma_f32_16x16x32_bf16(qf[f], kf, sfr[ct], 0, 0, 0);
      }

    const int qrow = q0 + w * 16 + l4 * 4;   // +reg
    float p0[4], p1[4], fsc[4];
    #pragma unroll
    for (int reg = 0; reg < 4; ++reg) {
      float s0 = sfr[0][reg] * scale;
      float s1 = sfr[1][reg] * scale;
      if (j0 + l15      > qrow + reg) s0 = -INFINITY;
      if (j0 + l15 + 16 > qrow + reg) s1 = -INFINITY;
      float tm = fmaxf(s0, s1);
      #pragma unroll
      for (int o = 1; o < 16; o <<= 1) tm = fmaxf(tm, __shfl_xor(tm, o));
      float Mnew = fmaxf(m_r[reg], tm);
      p0[reg] = __expf(s0 - Mnew);
      p1[reg] = __expf(s1 - Mnew);
      float psum = p0[reg] + p1[reg];
      #pragma unroll
      for (int o = 1; o < 16; o <<= 1) psum += __shfl_xor(psum, o);
      fsc[reg] = __expf(m_r[reg] - Mnew);
      m_r[reg] = Mnew;
      l_r[reg] = l_r[reg] * fsc[reg] + psum;
    }
    #pragma unroll
    for (int c = 0; c < 6; ++c)
      #pragma unroll
      for (int reg = 0; reg < 4; ++reg) acc[c][reg] *= fsc[reg];

    #pragma unroll
    for (int reg = 0; reg < 4; ++reg) {
      ps[w][l4 * 4 + reg][l15]      = f2bf(p0[reg]);
      ps[w][l4 * 4 + reg][l15 + 16] = f2bf(p1[reg]);
    }
    short8 pa = *reinterpret_cast<const short8*>(&ps[w][l15][l4 * 8]);

    #pragma unroll
    for (int c = 0; c < 6; ++c) {
      int h = c * 16 + l15;
      short8 vf = *reinterpret_cast<const short8*>(
          &vs[h][(l4 ^ ((h >> 3) & 3)) * 8]);   // un-swizzle tok group
      acc[c] = __builtin_amdgcn_mfma_f32_16x16x32_bf16(pa, vf, acc[c], 0, 0, 0);
    }
  }

  float inv[4];
  #pragma unroll
  for (int reg = 0; reg < 4; ++reg) inv[reg] = 1.f / l_r[reg];
  #pragma unroll
  for (int c = 0; c < 6; ++c) {
    #pragma unroll
    for (int reg = 0; reg < 4; ++reg) {
      size_t row = (size_t)(b * T_) + q0 + w * 16 + l4 * 4 + reg;
      out[row * H_ + c * 16 + l15] = acc[c][reg] * inv[reg];
    }
  }
}

extern "C" void kernel_launch(void* const* d_in, const int* in_sizes, int n_in,
                              void* d_out, int out_size, void* d_ws, size_t ws_size,
                              hipStream_t stream) {
  const float* x  = (const float*)d_in[0];
  const float* Wq = (const float*)d_in[1];
  const float* Wk = (const float*)d_in[2];
  const float* Wv = (const float*)d_in[3];

  short* wt = (short*)d_ws;                                // 442,368 B
  short* qb = (short*)((char*)d_ws + 524288);              // 6,291,456 B
  short* kb = qb + (size_t)M_ * H_;
  short* vb = kb + (size_t)M_ * H_;                        // row-major [M][96]
  float* outp = (float*)d_out;

  hipLaunchKernelGGL(wt_kernel, dim3((3*H_*D_ + 255)/256), dim3(256), 0, stream,
                     Wq, Wk, Wv, wt);
  hipLaunchKernelGGL(qkv_mfma_kernel, dim3(M_/64), dim3(256), 0, stream,
                     x, wt, qb, kb, vb);
  hipLaunchKernelGGL(attn_mfma_kernel, dim3(T_/QB, B_), dim3(128), 0, stream,
                     qb, kb, vb, outp);
}

// Round 18
// 85.462 us; speedup vs baseline: 1.1365x; 1.1365x over previous
//
#include <hip/hip_runtime.h>
#include <hip/hip_bf16.h>
#include <math.h>

#define B_ 64
#define T_ 512
#define D_ 768
#define H_ 96
#define M_ (B_*T_)   // 32768 rows

typedef __attribute__((ext_vector_type(8))) short short8;
typedef __attribute__((ext_vector_type(4))) float f32x4;

__device__ __forceinline__ short f2bf(float f) {
  unsigned u = __float_as_uint(f);
  unsigned r = (u + 0x7FFFu + ((u >> 16) & 1u)) >> 16;   // RTNE
  return (short)r;
}

__device__ __forceinline__ void gl16(const void* g, void* l) {
  __builtin_amdgcn_global_load_lds(
      (const __attribute__((address_space(1))) unsigned*)g,
      (__attribute__((address_space(3))) unsigned*)l, 16, 0, 0);
}

// ---------------------------------------------------------------------------
// Kernel 0: W -> bf16, transposed to [n][k] (n = mi*96+cc, 288 x 768).
// ---------------------------------------------------------------------------
__global__ __launch_bounds__(256) void wt_kernel(
    const float* __restrict__ Wq, const float* __restrict__ Wk,
    const float* __restrict__ Wv, short* __restrict__ wt)
{
  int id = blockIdx.x * 256 + threadIdx.x;     // 3*96*768 = 221184
  if (id >= 3*H_*D_) return;
  int n = id % 288;
  int k = id / 288;
  int mi = n / 96, cc = n % 96;
  const float* Wm = (mi == 0) ? Wq : ((mi == 1) ? Wk : Wv);
  wt[(size_t)n * D_ + k] = f2bf(Wm[(size_t)k * H_ + cc]);
}

// ---------------------------------------------------------------------------
// Kernel 1: QKV projection — revert to best-measured form (R12 staging +
// row-major v).  Rounds 5-17: seven structural variants pin at 57-72 us;
// this one is the plateau minimum.  No changes.
// ---------------------------------------------------------------------------
#define BKP 32

__global__ __launch_bounds__(256) void qkv_mfma_kernel(
    const float* __restrict__ x, const short* __restrict__ wt,
    short* __restrict__ qb, short* __restrict__ kb, short* __restrict__ vb)
{
  __shared__ float As[2][64][32];    // 16,384 B
  __shared__ short Bs[2][288][32];   // 36,864 B

  const int t    = threadIdx.x;
  const int row0 = blockIdx.x * 64;
  const int lane = t & 63;
  const int w    = t >> 6;
  const int l15  = lane & 15;
  const int l4   = lane >> 4;

  auto stageA = [&](int buf, int k0) {
    #pragma unroll
    for (int i = 0; i < 2; ++i) {
      int inst = w * 2 + i;
      int row  = inst * 8 + (lane >> 3);
      int c16  = (lane & 7) ^ ((lane >> 3) & 7);
      const char* g = (const char*)(x + (size_t)(row0 + row) * D_ + k0) + c16 * 16;
      char* l = (char*)&As[buf][0][0] + inst * 1024 + lane * 16;
      gl16(g, l);
    }
  };
  auto stageB = [&](int buf, int k0) {
    #pragma unroll
    for (int i = 0; i < 5; ++i) {
      int inst = w + 4 * i;
      if (inst < 18) {
        int row = inst * 16 + (lane >> 2);
        int c16 = (lane & 3) ^ ((lane >> 2) & 3);
        const char* g = (const char*)(wt + (size_t)row * D_ + k0) + c16 * 16;
        char* l = (char*)&Bs[buf][0][0] + inst * 1024 + lane * 16;
        gl16(g, l);
      }
    }
  };

  f32x4 acc[18];
  #pragma unroll
  for (int ci = 0; ci < 18; ++ci) acc[ci] = (f32x4){0.f, 0.f, 0.f, 0.f};

  stageA(0, 0);
  stageB(0, 0);
  __syncthreads();

  const int arow = w * 16 + l15;
  const char* Abase = (const char*)&As[0][0][0];
  const char* Bbase = (const char*)&Bs[0][0][0];

  for (int ks = 0; ks < 24; ++ks) {
    int buf = ks & 1;
    if (ks + 1 < 24) { stageA(buf ^ 1, (ks + 1) * BKP); stageB(buf ^ 1, (ks + 1) * BKP); }

    const char* ab = Abase + (size_t)buf * 8192 + arow * 128;
    float4 a0 = *reinterpret_cast<const float4*>(ab + (((l4 * 2 + 0) ^ (arow & 7)) * 16));
    float4 a1 = *reinterpret_cast<const float4*>(ab + (((l4 * 2 + 1) ^ (arow & 7)) * 16));
    short8 af;
    af[0] = f2bf(a0.x); af[1] = f2bf(a0.y); af[2] = f2bf(a0.z); af[3] = f2bf(a0.w);
    af[4] = f2bf(a1.x); af[5] = f2bf(a1.y); af[6] = f2bf(a1.z); af[7] = f2bf(a1.w);

    #pragma unroll
    for (int ci = 0; ci < 18; ++ci) {
      int brow = ci * 16 + l15;
      short8 bf = *reinterpret_cast<const short8*>(
          Bbase + (size_t)buf * 18432 + brow * 64 + ((l4 ^ (brow & 3)) * 16));
      acc[ci] = __builtin_amdgcn_mfma_f32_16x16x32_bf16(af, bf, acc[ci], 0, 0, 0);
    }
    __syncthreads();
  }

  const int rbase = row0 + w * 16 + l4 * 4;
  #pragma unroll
  for (int ci = 0; ci < 18; ++ci) {
    int mi = ci / 6;
    int cc = (ci % 6) * 16 + l15;
    short* Om = (mi == 0) ? qb : ((mi == 1) ? kb : vb);
    #pragma unroll
    for (int reg = 0; reg < 4; ++reg)
      Om[(size_t)(rbase + reg) * H_ + cc] = f2bf(acc[ci][reg]);
  }
}

// ---------------------------------------------------------------------------
// Kernel 2: causal flash attention, QB=64 (4 waves x 16 q-rows, 256 thr).
// Halves KV re-read traffic vs QB=32 (per-batch tile-loads 136 -> 36) and
// halves staging/barrier instances.  Per-wave math identical to the
// verified R13 kernel; fully-masked tiles for low waves are p=0-safe.
// ---------------------------------------------------------------------------
#define QB 64
#define KVB 32
#define KSTR 104
#define VSTR 40
#define PSTR 40

__global__ __launch_bounds__(256) void attn_mfma_kernel(
    const short* __restrict__ qb, const short* __restrict__ kb,
    const short* __restrict__ vb, float* __restrict__ out)
{
  __shared__ short ks[KVB][KSTR];     //  6,656 B
  __shared__ short vs[H_][VSTR];      //  7,680 B
  __shared__ short ps[4][16][PSTR];   //  5,120 B

  const int t    = threadIdx.x;
  const int lane = t & 63;
  const int w    = t >> 6;            // 0..3: wave owns q-rows q0+16w..+16
  const int l15  = lane & 15;
  const int l4   = lane >> 4;
  const int qi   = (T_/QB - 1) - blockIdx.x;   // heavy blocks first
  const int b    = blockIdx.y;
  const int q0   = qi * QB;

  short8 qf[3];
  {
    const short* qbase = qb + ((size_t)(b * T_) + q0 + w * 16 + l15) * H_;
    #pragma unroll
    for (int f = 0; f < 3; ++f)
      qf[f] = *reinterpret_cast<const short8*>(qbase + f * 32 + l4 * 8);
  }

  f32x4 acc[6];
  #pragma unroll
  for (int c = 0; c < 6; ++c) acc[c] = (f32x4){0.f, 0.f, 0.f, 0.f};
  float m_r[4] = {-INFINITY, -INFINITY, -INFINITY, -INFINITY};
  float l_r[4] = {0.f, 0.f, 0.f, 0.f};
  const float scale = 0.10206207261596576f;   // 1/sqrt(96)

  const int jmax = q0 + QB;
  for (int j0 = 0; j0 < jmax; j0 += KVB) {
    __syncthreads();
    {  // stage K tile: 32 rows x 96 bf16 = 384 short8 chunks (256 threads)
      #pragma unroll
      for (int i = 0; i < 2; ++i) {
        int c = t + i * 256;
        if (c < 384) {
          int row = c / 12, seg = c % 12;
          *reinterpret_cast<short8*>(&ks[row][seg * 8]) =
              *reinterpret_cast<const short8*>(
                  kb + (size_t)(b * T_ + j0 + row) * H_ + seg * 8);
        }
      }
    }
    {  // stage V tile: transpose 32 tok x 96 h -> vs[h][tokS]
      #pragma unroll
      for (int i = 0; i < 2; ++i) {
        int c = t + i * 256;
        if (c < 384) {
          int tok = c / 12;
          int m   = c % 12;
          int h0  = m * 8;
          short8 v = *reinterpret_cast<const short8*>(
              vb + (size_t)(b * T_ + j0 + tok) * H_ + h0);
          int tokS = tok ^ ((m & 3) << 3);
          #pragma unroll
          for (int j = 0; j < 8; ++j) vs[h0 + j][tokS] = v[j];
        }
      }
    }
    __syncthreads();

    f32x4 sfr[2];
    sfr[0] = (f32x4){0.f,0.f,0.f,0.f};
    sfr[1] = (f32x4){0.f,0.f,0.f,0.f};
    #pragma unroll
    for (int ct = 0; ct < 2; ++ct)
      #pragma unroll
      for (int f = 0; f < 3; ++f) {
        short8 kf = *reinterpret_cast<const short8*>(&ks[ct * 16 + l15][f * 32 + l4 * 8]);
        sfr[ct] = __builtin_amdgcn_mfma_f32_16x16x32_bf16(qf[f], kf, sfr[ct], 0, 0, 0);
      }

    const int qrow = q0 + w * 16 + l4 * 4;   // +reg
    float p0[4], p1[4], fsc[4];
    #pragma unroll
    for (int reg = 0; reg < 4; ++reg) {
      float s0 = sfr[0][reg] * scale;
      float s1 = sfr[1][reg] * scale;
      if (j0 + l15      > qrow + reg) s0 = -INFINITY;
      if (j0 + l15 + 16 > qrow + reg) s1 = -INFINITY;
      float tm = fmaxf(s0, s1);
      #pragma unroll
      for (int o = 1; o < 16; o <<= 1) tm = fmaxf(tm, __shfl_xor(tm, o));
      float Mnew = fmaxf(m_r[reg], tm);           // tm=-inf (all-masked) -> Mnew=m_r
      p0[reg] = __expf(s0 - Mnew);
      p1[reg] = __expf(s1 - Mnew);
      float psum = p0[reg] + p1[reg];
      #pragma unroll
      for (int o = 1; o < 16; o <<= 1) psum += __shfl_xor(psum, o);
      fsc[reg] = __expf(m_r[reg] - Mnew);         // all-masked tile -> fsc=1
      m_r[reg] = Mnew;
      l_r[reg] = l_r[reg] * fsc[reg] + psum;
    }
    #pragma unroll
    for (int c = 0; c < 6; ++c)
      #pragma unroll
      for (int reg = 0; reg < 4; ++reg) acc[c][reg] *= fsc[reg];

    #pragma unroll
    for (int reg = 0; reg < 4; ++reg) {
      ps[w][l4 * 4 + reg][l15]      = f2bf(p0[reg]);
      ps[w][l4 * 4 + reg][l15 + 16] = f2bf(p1[reg]);
    }
    short8 pa = *reinterpret_cast<const short8*>(&ps[w][l15][l4 * 8]);

    #pragma unroll
    for (int c = 0; c < 6; ++c) {
      int h = c * 16 + l15;
      short8 vf = *reinterpret_cast<const short8*>(
          &vs[h][(l4 ^ ((h >> 3) & 3)) * 8]);
      acc[c] = __builtin_amdgcn_mfma_f32_16x16x32_bf16(pa, vf, acc[c], 0, 0, 0);
    }
  }

  float inv[4];
  #pragma unroll
  for (int reg = 0; reg < 4; ++reg) inv[reg] = 1.f / l_r[reg];
  #pragma unroll
  for (int c = 0; c < 6; ++c) {
    #pragma unroll
    for (int reg = 0; reg < 4; ++reg) {
      size_t row = (size_t)(b * T_) + q0 + w * 16 + l4 * 4 + reg;
      out[row * H_ + c * 16 + l15] = acc[c][reg] * inv[reg];
    }
  }
}

extern "C" void kernel_launch(void* const* d_in, const int* in_sizes, int n_in,
                              void* d_out, int out_size, void* d_ws, size_t ws_size,
                              hipStream_t stream) {
  const float* x  = (const float*)d_in[0];
  const float* Wq = (const float*)d_in[1];
  const float* Wk = (const float*)d_in[2];
  const float* Wv = (const float*)d_in[3];

  short* wt = (short*)d_ws;                                // 442,368 B
  short* qb = (short*)((char*)d_ws + 524288);              // 6,291,456 B
  short* kb = qb + (size_t)M_ * H_;
  short* vb = kb + (size_t)M_ * H_;                        // row-major [M][96]
  float* outp = (float*)d_out;

  hipLaunchKernelGGL(wt_kernel, dim3((3*H_*D_ + 255)/256), dim3(256), 0, stream,
                     Wq, Wk, Wv, wt);
  hipLaunchKernelGGL(qkv_mfma_kernel, dim3(M_/64), dim3(256), 0, stream,
                     x, wt, qb, kb, vb);
  hipLaunchKernelGGL(attn_mfma_kernel, dim3(T_/QB, B_), dim3(256), 0, stream,
                     qb, kb, vb, outp);
}

// Round 19
// 75.625 us; speedup vs baseline: 1.2843x; 1.1301x over previous
//
#include <hip/hip_runtime.h>
#include <hip/hip_bf16.h>
#include <math.h>

// ============================================================================
// FINAL CONFIG = round-12 exact (session minimum, 75.39 us timed).
// Ledger: every post-R12 lever regressed — R13 v-coalesce +6, R14 W-resident
// +132, R15 counted-vmcnt +16, R16 BN-split +4, R17 A-resident +22, R18
// QB64 +10.  Eight qkv structures pin at 57-72 us profiled with all pipes
// idle (MfmaUtil<=9.5, VALUBusy<=17, HBM<=16%) -> small-dispatch latency/
// clock plateau, not a pipe roofline reachable from source here.
// ============================================================================

#define B_ 64
#define T_ 512
#define D_ 768
#define H_ 96
#define M_ (B_*T_)   // 32768 rows

typedef __attribute__((ext_vector_type(8))) short short8;
typedef __attribute__((ext_vector_type(4))) float f32x4;

__device__ __forceinline__ short f2bf(float f) {
  unsigned u = __float_as_uint(f);
  unsigned r = (u + 0x7FFFu + ((u >> 16) & 1u)) >> 16;   // RTNE
  return (short)r;
}

__device__ __forceinline__ void gl16(const void* g, void* l) {
  __builtin_amdgcn_global_load_lds(
      (const __attribute__((address_space(1))) unsigned*)g,
      (__attribute__((address_space(3))) unsigned*)l, 16, 0, 0);
}

// ---------------------------------------------------------------------------
// Kernel 0: W -> bf16, transposed to [n][k] (n = mi*96+cc, 288 x 768).
// ---------------------------------------------------------------------------
__global__ __launch_bounds__(256) void wt_kernel(
    const float* __restrict__ Wq, const float* __restrict__ Wk,
    const float* __restrict__ Wv, short* __restrict__ wt)
{
  int id = blockIdx.x * 256 + threadIdx.x;     // 3*96*768 = 221184
  if (id >= 3*H_*D_) return;
  int n = id % 288;
  int k = id / 288;
  int mi = n / 96, cc = n % 96;
  const float* Wm = (mi == 0) ? Wq : ((mi == 1) ? Wk : Wv);
  wt[(size_t)n * D_ + k] = f2bf(Wm[(size_t)k * H_ + cc]);
}

// ---------------------------------------------------------------------------
// Kernel 1: QKV projection, global_load_lds GEMM (R12 exact).
// BM=64 x BK=32, 4 waves x (16 rows x 288 cols), acc[18]=72 VGPR.
// Linear LDS dest + XOR-pre-swizzled global source + same-XOR read.
// q,k row-major bf16 [M][96]; v scatter-stored pre-transposed [B][96][T].
// ---------------------------------------------------------------------------
#define BKP 32

__global__ __launch_bounds__(256) void qkv_mfma_kernel(
    const float* __restrict__ x, const short* __restrict__ wt,
    short* __restrict__ qb, short* __restrict__ kb, short* __restrict__ vtp)
{
  __shared__ float As[2][64][32];    // 16,384 B
  __shared__ short Bs[2][288][32];   // 36,864 B

  const int t    = threadIdx.x;
  const int row0 = blockIdx.x * 64;
  const int lane = t & 63;
  const int w    = t >> 6;
  const int l15  = lane & 15;
  const int l4   = lane >> 4;

  auto stageA = [&](int buf, int k0) {
    #pragma unroll
    for (int i = 0; i < 2; ++i) {
      int inst = w * 2 + i;
      int row  = inst * 8 + (lane >> 3);
      int c16  = (lane & 7) ^ ((lane >> 3) & 7);
      const char* g = (const char*)(x + (size_t)(row0 + row) * D_ + k0) + c16 * 16;
      char* l = (char*)&As[buf][0][0] + inst * 1024 + lane * 16;
      gl16(g, l);
    }
  };
  auto stageB = [&](int buf, int k0) {
    #pragma unroll
    for (int i = 0; i < 5; ++i) {
      int inst = w + 4 * i;
      if (inst < 18) {
        int row = inst * 16 + (lane >> 2);
        int c16 = (lane & 3) ^ ((lane >> 2) & 3);
        const char* g = (const char*)(wt + (size_t)row * D_ + k0) + c16 * 16;
        char* l = (char*)&Bs[buf][0][0] + inst * 1024 + lane * 16;
        gl16(g, l);
      }
    }
  };

  f32x4 acc[18];
  #pragma unroll
  for (int ci = 0; ci < 18; ++ci) acc[ci] = (f32x4){0.f, 0.f, 0.f, 0.f};

  stageA(0, 0);
  stageB(0, 0);
  __syncthreads();

  const int arow = w * 16 + l15;
  const char* Abase = (const char*)&As[0][0][0];
  const char* Bbase = (const char*)&Bs[0][0][0];

  for (int ks = 0; ks < 24; ++ks) {
    int buf = ks & 1;
    if (ks + 1 < 24) { stageA(buf ^ 1, (ks + 1) * BKP); stageB(buf ^ 1, (ks + 1) * BKP); }

    const char* ab = Abase + (size_t)buf * 8192 + arow * 128;
    float4 a0 = *reinterpret_cast<const float4*>(ab + (((l4 * 2 + 0) ^ (arow & 7)) * 16));
    float4 a1 = *reinterpret_cast<const float4*>(ab + (((l4 * 2 + 1) ^ (arow & 7)) * 16));
    short8 af;
    af[0] = f2bf(a0.x); af[1] = f2bf(a0.y); af[2] = f2bf(a0.z); af[3] = f2bf(a0.w);
    af[4] = f2bf(a1.x); af[5] = f2bf(a1.y); af[6] = f2bf(a1.z); af[7] = f2bf(a1.w);

    #pragma unroll
    for (int ci = 0; ci < 18; ++ci) {
      int brow = ci * 16 + l15;
      short8 bf = *reinterpret_cast<const short8*>(
          Bbase + (size_t)buf * 18432 + brow * 64 + ((l4 ^ (brow & 3)) * 16));
      acc[ci] = __builtin_amdgcn_mfma_f32_16x16x32_bf16(af, bf, acc[ci], 0, 0, 0);
    }
    __syncthreads();
  }

  // epilogue: acc[ci]: rows = row0 + w*16 + l4*4 + reg, col = ci*16 + l15
  const int rbase = row0 + w * 16 + l4 * 4;
  #pragma unroll
  for (int ci = 0; ci < 18; ++ci) {
    int mi = ci / 6;
    int cc = (ci % 6) * 16 + l15;
    if (mi == 2) {
      int bb = rbase / T_, tl = rbase % T_;     // 4 tokens, same batch (4 | T)
      short4 pk;
      pk.x = f2bf(acc[ci][0]); pk.y = f2bf(acc[ci][1]);
      pk.z = f2bf(acc[ci][2]); pk.w = f2bf(acc[ci][3]);
      *reinterpret_cast<short4*>(vtp + ((size_t)bb * H_ + cc) * T_ + tl) = pk;
    } else {
      short* Om = (mi == 0) ? qb : kb;
      #pragma unroll
      for (int reg = 0; reg < 4; ++reg)
        Om[(size_t)(rbase + reg) * H_ + cc] = f2bf(acc[ci][reg]);
    }
  }
}

// ---------------------------------------------------------------------------
// Kernel 2: causal flash attention via MFMA bf16 (R12 exact).
// Block 128 thr = 2 waves x 16 q-rows; KV tiles of 32; V read from the
// pre-transposed vtp [B][96][T] (no in-kernel transpose).
// ---------------------------------------------------------------------------
#define QB 32
#define KVB 32
#define KSTR 104
#define VSTR 40
#define PSTR 40

__global__ __launch_bounds__(128) void attn_mfma_kernel(
    const short* __restrict__ qb, const short* __restrict__ kb,
    const short* __restrict__ vtp, float* __restrict__ out)
{
  __shared__ short ks[KVB][KSTR];     // 6656 B
  __shared__ short vs[H_][VSTR];      // 7680 B
  __shared__ short ps[2][16][PSTR];   // 2560 B

  const int t    = threadIdx.x;
  const int lane = t & 63;
  const int w    = t >> 6;            // 0..1
  const int l15  = lane & 15;
  const int l4   = lane >> 4;
  const int qi   = 15 - blockIdx.x;   // heavy blocks first
  const int b    = blockIdx.y;
  const int q0   = qi * QB;

  short8 qf[3];
  {
    const short* qbase = qb + ((size_t)(b * T_) + q0 + w * 16 + l15) * H_;
    #pragma unroll
    for (int f = 0; f < 3; ++f)
      qf[f] = *reinterpret_cast<const short8*>(qbase + f * 32 + l4 * 8);
  }

  f32x4 acc[6];
  #pragma unroll
  for (int c = 0; c < 6; ++c) acc[c] = (f32x4){0.f, 0.f, 0.f, 0.f};
  float m_r[4] = {-INFINITY, -INFINITY, -INFINITY, -INFINITY};
  float l_r[4] = {0.f, 0.f, 0.f, 0.f};
  const float scale = 0.10206207261596576f;   // 1/sqrt(96)

  const int jmax = q0 + QB;
  for (int j0 = 0; j0 < jmax; j0 += KVB) {
    __syncthreads();
    {  // stage K tile: 32 rows x 96 bf16
      int row = t >> 2, seg = t & 3;
      const short* src = kb + ((size_t)(b * T_) + j0 + row) * H_ + seg * 24;
      short* dst = &ks[row][seg * 24];
      *reinterpret_cast<short8*>(dst)      = *reinterpret_cast<const short8*>(src);
      *reinterpret_cast<short8*>(dst + 8)  = *reinterpret_cast<const short8*>(src + 8);
      *reinterpret_cast<short8*>(dst + 16) = *reinterpret_cast<const short8*>(src + 16);
    }
    {  // stage V tile: 96 h x 32 keys (pre-transposed in global)
      #pragma unroll
      for (int i = 0; i < 3; ++i) {
        int c = t + i * 128;
        int h = c >> 2, k8 = c & 3;
        *reinterpret_cast<short8*>(&vs[h][k8 * 8]) =
            *reinterpret_cast<const short8*>(vtp + ((size_t)b * H_ + h) * T_ + j0 + k8 * 8);
      }
    }
    __syncthreads();

    f32x4 sfr[2];
    sfr[0] = (f32x4){0.f,0.f,0.f,0.f};
    sfr[1] = (f32x4){0.f,0.f,0.f,0.f};
    #pragma unroll
    for (int ct = 0; ct < 2; ++ct)
      #pragma unroll
      for (int f = 0; f < 3; ++f) {
        short8 kf = *reinterpret_cast<const short8*>(&ks[ct * 16 + l15][f * 32 + l4 * 8]);
        sfr[ct] = __builtin_amdgcn_mfma_f32_16x16x32_bf16(qf[f], kf, sfr[ct], 0, 0, 0);
      }

    const int qrow = q0 + w * 16 + l4 * 4;   // +reg
    float p0[4], p1[4], fsc[4];
    #pragma unroll
    for (int reg = 0; reg < 4; ++reg) {
      float s0 = sfr[0][reg] * scale;
      float s1 = sfr[1][reg] * scale;
      if (j0 + l15      > qrow + reg) s0 = -INFINITY;
      if (j0 + l15 + 16 > qrow + reg) s1 = -INFINITY;
      float tm = fmaxf(s0, s1);
      #pragma unroll
      for (int o = 1; o < 16; o <<= 1) tm = fmaxf(tm, __shfl_xor(tm, o));
      float Mnew = fmaxf(m_r[reg], tm);
      p0[reg] = __expf(s0 - Mnew);
      p1[reg] = __expf(s1 - Mnew);
      float psum = p0[reg] + p1[reg];
      #pragma unroll
      for (int o = 1; o < 16; o <<= 1) psum += __shfl_xor(psum, o);
      fsc[reg] = __expf(m_r[reg] - Mnew);
      m_r[reg] = Mnew;
      l_r[reg] = l_r[reg] * fsc[reg] + psum;
    }
    #pragma unroll
    for (int c = 0; c < 6; ++c)
      #pragma unroll
      for (int reg = 0; reg < 4; ++reg) acc[c][reg] *= fsc[reg];

    #pragma unroll
    for (int reg = 0; reg < 4; ++reg) {
      ps[w][l4 * 4 + reg][l15]      = f2bf(p0[reg]);
      ps[w][l4 * 4 + reg][l15 + 16] = f2bf(p1[reg]);
    }
    short8 pa = *reinterpret_cast<const short8*>(&ps[w][l15][l4 * 8]);

    #pragma unroll
    for (int c = 0; c < 6; ++c) {
      short8 vf = *reinterpret_cast<const short8*>(&vs[c * 16 + l15][l4 * 8]);
      acc[c] = __builtin_amdgcn_mfma_f32_16x16x32_bf16(pa, vf, acc[c], 0, 0, 0);
    }
  }

  float inv[4];
  #pragma unroll
  for (int reg = 0; reg < 4; ++reg) inv[reg] = 1.f / l_r[reg];
  #pragma unroll
  for (int c = 0; c < 6; ++c) {
    #pragma unroll
    for (int reg = 0; reg < 4; ++reg) {
      size_t row = (size_t)(b * T_) + q0 + w * 16 + l4 * 4 + reg;
      out[row * H_ + c * 16 + l15] = acc[c][reg] * inv[reg];
    }
  }
}

extern "C" void kernel_launch(void* const* d_in, const int* in_sizes, int n_in,
                              void* d_out, int out_size, void* d_ws, size_t ws_size,
                              hipStream_t stream) {
  const float* x  = (const float*)d_in[0];
  const float* Wq = (const float*)d_in[1];
  const float* Wk = (const float*)d_in[2];
  const float* Wv = (const float*)d_in[3];

  short* wt  = (short*)d_ws;                               // 442,368 B
  short* qb  = (short*)((char*)d_ws + 524288);             // 6,291,456 B
  short* kb  = qb + (size_t)M_ * H_;
  short* vtp = kb + (size_t)M_ * H_;                       // [B][96][T]
  float* outp = (float*)d_out;

  hipLaunchKernelGGL(wt_kernel, dim3((3*H_*D_ + 255)/256), dim3(256), 0, stream,
                     Wq, Wk, Wv, wt);
  hipLaunchKernelGGL(qkv_mfma_kernel, dim3(M_/64), dim3(256), 0, stream,
                     x, wt, qb, kb, vtp);
  hipLaunchKernelGGL(attn_mfma_kernel, dim3(T_/QB, B_), dim3(128), 0, stream,
                     qb, kb, vtp, outp);
}